// Round 1
// baseline (471.889 us; speedup 1.0000x reference)
//
#include <hip/hip_runtime.h>
#include <hip/hip_bf16.h>

#define S_TOT 2720
#define DMODEL 128

// ---------------- down projection: t0[b,pos,c] = x[b,pos,:] @ w_down + b_down
__global__ void down_kernel(const float* __restrict__ x, const float* __restrict__ w,
                            const float* __restrict__ b, float* __restrict__ t0) {
    int id = blockIdx.x * 256 + threadIdx.x;     // B*2048*32 = 131072
    int c = id & 31;
    int r = id >> 5;                             // b*2048 + pos
    const float* xr = x + r * 128;
    float acc = b[c];
#pragma unroll 8
    for (int k = 0; k < 128; ++k) acc += xr[k] * w[k * 32 + c];
    t0[id] = acc;
}

// ---------------- conv (stride4,k4) + bias + BN + ELU, writes into pooled rows
__global__ void conv_kernel(const float* __restrict__ in, float* __restrict__ pooled,
                            const float* __restrict__ cw, const float* __restrict__ cb,
                            const float* __restrict__ bg, const float* __restrict__ bb,
                            const float* __restrict__ bm, const float* __restrict__ bv,
                            int level, int in_bstride, int in_off, int Lout, int out_off,
                            int total) {
    int id = blockIdx.x * 256 + threadIdx.x;
    if (id >= total) return;
    int co = id & 31;
    int lo = (id >> 5) % Lout;
    int b  = id / (32 * Lout);
    const float* ib = in + (size_t)(b * in_bstride + in_off + lo * 4) * 32;
    const float* w  = cw + (size_t)(level * 32 + co) * 32 * 4;
    float acc = cb[level * 32 + co];
#pragma unroll
    for (int ci = 0; ci < 32; ++ci)
#pragma unroll
        for (int k = 0; k < 4; ++k)
            acc += ib[k * 32 + ci] * w[ci * 4 + k];
    acc = (acc - bm[level * 32 + co]) * rsqrtf(bv[level * 32 + co] + 1e-5f)
          * bg[level * 32 + co] + bb[level * 32 + co];
    acc = acc > 0.f ? acc : expm1f(acc);
    pooled[(size_t)(b * 672 + out_off + lo) * 32 + co] = acc;
}

// ---------------- h_pre = concat([x, pooled @ w_up + b_up], axis=seq)
__global__ void build_h_kernel(const float* __restrict__ x, const float* __restrict__ pooled,
                               const float* __restrict__ w_up, const float* __restrict__ b_up,
                               float* __restrict__ out) {
    int id = blockIdx.x * 256 + threadIdx.x;     // B*2720*128 = 696320
    int d = id & 127;
    int s = (id >> 7) % S_TOT;
    int b = id / (S_TOT * 128);
    float val;
    if (s < 2048) {
        val = x[(size_t)(b * 2048 + s) * 128 + d];
    } else {
        int p = s - 2048;
        const float* pr = pooled + (size_t)(b * 672 + p) * 32;
        float acc = b_up[d];
#pragma unroll
        for (int k = 0; k < 32; ++k) acc += pr[k] * w_up[k * 128 + d];
        val = acc;
    }
    out[id] = val;
}

// ---------------- LayerNorm over 128, optional residual. wave(64) per row, 2 elems/lane.
// In-place safe: each thread reads exactly the elements it writes, before writing.
__global__ void ln_kernel(const float* __restrict__ A, const float* __restrict__ R,
                          const float* __restrict__ g, const float* __restrict__ bta,
                          float* __restrict__ out, int nrows, float eps) {
    int wave = threadIdx.x >> 6;
    int lane = threadIdx.x & 63;
    int row = blockIdx.x * 4 + wave;
    if (row >= nrows) return;
    const float* a = A + (size_t)row * 128;
    float v0 = a[lane], v1 = a[lane + 64];
    if (R) {
        const float* rr = R + (size_t)row * 128;
        v0 += rr[lane]; v1 += rr[lane + 64];
    }
    float sum = v0 + v1;
#pragma unroll
    for (int off = 32; off; off >>= 1) sum += __shfl_xor(sum, off);
    float mu = sum * (1.f / 128.f);
    float d0 = v0 - mu, d1 = v1 - mu;
    float vs = d0 * d0 + d1 * d1;
#pragma unroll
    for (int off = 32; off; off >>= 1) vs += __shfl_xor(vs, off);
    float inv = rsqrtf(vs * (1.f / 128.f) + eps);
    out[(size_t)row * 128 + lane]      = d0 * inv * g[lane]      + bta[lane];
    out[(size_t)row * 128 + lane + 64] = d1 * inv * g[lane + 64] + bta[lane + 64];
}

// ---------------- generic 128x128 matmul: C[r,:] = A[r,:] @ W (+bias)
__global__ void matmul128_kernel(const float* __restrict__ A, const float* __restrict__ W,
                                 const float* __restrict__ bias, float* __restrict__ C,
                                 int nrows) {
    int tid = threadIdx.x;
    int r = blockIdx.x * 2 + (tid >> 7);
    int n = tid & 127;
    if (r >= nrows) return;
    const float* a = A + (size_t)r * 128;
    float acc = bias ? bias[n] : 0.f;
#pragma unroll 8
    for (int k = 0; k < 128; ++k) acc += a[k] * W[k * 128 + n];
    C[(size_t)r * 128 + n] = acc;
}

// ---------------- sparse pyramid attention: each query has <=10 neighbors
// slots: 0..4 intra-scale window (i-2..i+2), 5 parent, 6..9 children
__global__ void attn_kernel(const float* __restrict__ Q, const float* __restrict__ K,
                            const float* __restrict__ V, float* __restrict__ O) {
    int id = blockIdx.x * 256 + threadIdx.x;     // B*4*2720 = 21760
    if (id >= 21760) return;
    int i  = id % S_TOT;
    int hh = (id / S_TOT) & 3;
    int b  = id / (S_TOT * 4);
    int li, s, sz;
    if (i < 2048)      { li = 0; s = 0;    sz = 2048; }
    else if (i < 2560) { li = 1; s = 2048; sz = 512; }
    else if (i < 2688) { li = 2; s = 2560; sz = 128; }
    else               { li = 3; s = 2688; sz = 32; }
    int pstart = (li == 0) ? 2048 : (li == 1) ? 2560 : 2688;   // parent scale start (li<3)
    int cstart = (li == 1) ? 0 : (li == 2) ? 2048 : 2560;      // child scale start  (li>0)

    const float* qp = Q + ((size_t)(b * S_TOT + i) * 128) + hh * 32;
    float qr[32];
#pragma unroll
    for (int d = 0; d < 32; ++d) qr[d] = qp[d];
    const float invt = 0.17677669529663687f;     // 1/sqrt(32)

    float sc[10];
    int   nj[10];
    bool  vl[10];
#pragma unroll
    for (int slot = 0; slot < 10; ++slot) {
        int j; bool valid;
        if (slot < 5)       { j = i - 2 + slot;                         valid = (j >= s) && (j < s + sz); }
        else if (slot == 5) { j = pstart + ((i - s) >> 2);              valid = (li < 3); }
        else                { j = cstart + ((i - s) << 2) + (slot - 6); valid = (li > 0); }
        nj[slot] = j; vl[slot] = valid;
        if (valid) {
            const float* kp = K + ((size_t)(b * S_TOT + j) * 128) + hh * 32;
            float dot = 0.f;
#pragma unroll
            for (int d = 0; d < 32; ++d) dot += qr[d] * kp[d];
            sc[slot] = dot * invt;
        } else {
            sc[slot] = -1e30f;
        }
    }
    float mx = sc[0];
#pragma unroll
    for (int slot = 1; slot < 10; ++slot) mx = fmaxf(mx, sc[slot]);
    float ssum = 0.f;
#pragma unroll
    for (int slot = 0; slot < 10; ++slot) { sc[slot] = expf(sc[slot] - mx); ssum += sc[slot]; }
    float rinv = 1.f / ssum;
    float oa[32];
#pragma unroll
    for (int d = 0; d < 32; ++d) oa[d] = 0.f;
#pragma unroll
    for (int slot = 0; slot < 10; ++slot) {
        if (vl[slot]) {
            float p = sc[slot] * rinv;
            const float* vp = V + ((size_t)(b * S_TOT + nj[slot]) * 128) + hh * 32;
#pragma unroll
            for (int d = 0; d < 32; ++d) oa[d] += p * vp[d];
        }
    }
    float* op = O + ((size_t)(b * S_TOT + i) * 128) + hh * 32;
#pragma unroll
    for (int d = 0; d < 32; ++d) op[d] = oa[d];
}

// ---------------- fused FFN: out = relu(h@w1+b1)@w2 + b2 (one block=512 thr per row)
__global__ void ffn_kernel(const float* __restrict__ H, const float* __restrict__ w1,
                           const float* __restrict__ b1, const float* __restrict__ w2,
                           const float* __restrict__ b2, float* __restrict__ out) {
    __shared__ float f1[512];
    __shared__ float part[4][128];
    int r = blockIdx.x;
    int tid = threadIdx.x;
    const float* h = H + (size_t)r * 128;
    float acc = b1[tid];
#pragma unroll 8
    for (int k = 0; k < 128; ++k) acc += h[k] * w1[k * 512 + tid];
    f1[tid] = fmaxf(acc, 0.f);
    __syncthreads();
    int d = tid & 127, seg = tid >> 7;
    float p = 0.f;
#pragma unroll 8
    for (int j = 0; j < 128; ++j) p += f1[seg * 128 + j] * w2[(size_t)(seg * 128 + j) * 128 + d];
    part[seg][d] = p;
    __syncthreads();
    if (tid < 128)
        out[(size_t)r * 128 + tid] = part[0][tid] + part[1][tid] + part[2][tid] + part[3][tid] + b2[tid];
}

// ---------------- gather refer-points: out[b,t,j*128+d] = h[b, idx[t,j], d]
__global__ void gather_kernel(const float* __restrict__ H, const int* __restrict__ idx,
                              float* __restrict__ out) {
    int id = blockIdx.x * 256 + threadIdx.x;     // 2*2048*512 = 2^21
    int d = id & 127;
    int j = (id >> 7) & 3;
    int t = (id >> 9) & 2047;
    int b = id >> 20;
    int src = idx[t * 4 + j];
    out[id] = H[((size_t)(b * S_TOT + src) * 128) + d];
}

extern "C" void kernel_launch(void* const* d_in, const int* in_sizes, int n_in,
                              void* d_out, int out_size, void* d_ws, size_t ws_size,
                              hipStream_t stream) {
    (void)in_sizes; (void)n_in; (void)out_size; (void)ws_size;
    const float* x       = (const float*)d_in[0];
    const float* w_down  = (const float*)d_in[1];
    const float* b_down  = (const float*)d_in[2];
    const float* conv_w  = (const float*)d_in[3];
    const float* conv_b  = (const float*)d_in[4];
    const float* bn_g    = (const float*)d_in[5];
    const float* bn_b    = (const float*)d_in[6];
    const float* bn_m    = (const float*)d_in[7];
    const float* bn_v    = (const float*)d_in[8];
    const float* w_up    = (const float*)d_in[9];
    const float* b_up    = (const float*)d_in[10];
    const float* ln0_g   = (const float*)d_in[11];
    const float* ln0_b   = (const float*)d_in[12];
    const float* wq      = (const float*)d_in[13];
    const float* wk      = (const float*)d_in[14];
    const float* wv      = (const float*)d_in[15];
    const float* wo      = (const float*)d_in[16];
    const float* ln1_g   = (const float*)d_in[17];
    const float* ln1_b   = (const float*)d_in[18];
    const float* ffn_w1  = (const float*)d_in[19];
    const float* ffn_b1  = (const float*)d_in[20];
    const float* ffn_w2  = (const float*)d_in[21];
    const float* ffn_b2  = (const float*)d_in[22];
    const float* ln2_g   = (const float*)d_in[23];
    const float* ln2_b   = (const float*)d_in[24];
    // d_in[25] = mask (bool) — unused: mask structure computed arithmetically
    const int* indexes   = (const int*)d_in[26];

    float* ws = (float*)d_ws;
    float* t0     = ws;               // 131072
    float* pooled = ws + 131072;      // 43008
    float* h      = ws + 174080;      // 696320
    float* q      = ws + 870400;      // 696320
    float* k      = ws + 1566720;     // 696320
    float* v      = ws + 2263040;     // 696320
    float* o      = ws + 2959360;     // 696320
    float* tmp    = ws + 3655680;     // 696320

    down_kernel<<<512, 256, 0, stream>>>(x, w_down, b_down, t0);
    conv_kernel<<<128, 256, 0, stream>>>(t0, pooled, conv_w, conv_b, bn_g, bn_b, bn_m, bn_v,
                                         0, 2048, 0, 512, 0, 32768);
    conv_kernel<<<32, 256, 0, stream>>>(pooled, pooled, conv_w, conv_b, bn_g, bn_b, bn_m, bn_v,
                                        1, 672, 0, 128, 512, 8192);
    conv_kernel<<<8, 256, 0, stream>>>(pooled, pooled, conv_w, conv_b, bn_g, bn_b, bn_m, bn_v,
                                       2, 672, 512, 32, 640, 2048);
    build_h_kernel<<<2720, 256, 0, stream>>>(x, pooled, w_up, b_up, tmp);
    ln_kernel<<<1360, 256, 0, stream>>>(tmp, nullptr, ln0_g, ln0_b, h, 5440, 1e-5f);

    for (int l = 0; l < 2; ++l) {
        matmul128_kernel<<<2720, 256, 0, stream>>>(h, wq + l * 16384, nullptr, q, 5440);
        matmul128_kernel<<<2720, 256, 0, stream>>>(h, wk + l * 16384, nullptr, k, 5440);
        matmul128_kernel<<<2720, 256, 0, stream>>>(h, wv + l * 16384, nullptr, v, 5440);
        attn_kernel<<<85, 256, 0, stream>>>(q, k, v, o);
        matmul128_kernel<<<2720, 256, 0, stream>>>(o, wo + l * 16384, nullptr, tmp, 5440);
        ln_kernel<<<1360, 256, 0, stream>>>(tmp, h, ln1_g + l * 128, ln1_b + l * 128, h, 5440, 1e-6f);
        ffn_kernel<<<5440, 512, 0, stream>>>(h, ffn_w1 + l * 65536, ffn_b1 + l * 512,
                                             ffn_w2 + l * 65536, ffn_b2 + l * 128, tmp);
        ln_kernel<<<1360, 256, 0, stream>>>(tmp, h, ln2_g + l * 128, ln2_b + l * 128, h, 5440, 1e-6f);
    }
    gather_kernel<<<8192, 256, 0, stream>>>(h, indexes, (float*)d_out);
}

// Round 2
// 192.410 us; speedup vs baseline: 2.4525x; 2.4525x over previous
//
#include <hip/hip_runtime.h>
#include <hip/hip_bf16.h>

#define S_TOT 2720

// ---------------- down projection: t0[b,pos,c] = x[b,pos,:] @ w_down + b_down
__global__ void down_kernel(const float* __restrict__ x, const float* __restrict__ w,
                            const float* __restrict__ b, float* __restrict__ t0) {
    int id = blockIdx.x * 256 + threadIdx.x;     // B*2048*32 = 131072
    int c = id & 31;
    int r = id >> 5;
    const float* xr = x + (size_t)r * 128;
    float a0 = b[c], a1 = 0.f, a2 = 0.f, a3 = 0.f;
#pragma unroll
    for (int k = 0; k < 128; k += 4) {
        a0 += xr[k]     * w[(k)     * 32 + c];
        a1 += xr[k + 1] * w[(k + 1) * 32 + c];
        a2 += xr[k + 2] * w[(k + 2) * 32 + c];
        a3 += xr[k + 3] * w[(k + 3) * 32 + c];
    }
    t0[id] = (a0 + a1) + (a2 + a3);
}

// ---------------- conv (stride4,k4) + bias + BN + ELU
__global__ void conv_kernel(const float* __restrict__ in, float* __restrict__ pooled,
                            const float* __restrict__ cw, const float* __restrict__ cb,
                            const float* __restrict__ bg, const float* __restrict__ bb,
                            const float* __restrict__ bm, const float* __restrict__ bv,
                            int level, int in_bstride, int in_off, int Lout, int out_off,
                            int total) {
    int id = blockIdx.x * 256 + threadIdx.x;
    if (id >= total) return;
    int co = id & 31;
    int lo = (id >> 5) % Lout;
    int b  = id / (32 * Lout);
    const float* ib = in + (size_t)(b * in_bstride + in_off + lo * 4) * 32;
    const float* w  = cw + (size_t)(level * 32 + co) * 32 * 4;
    float acc0 = 0.f, acc1 = 0.f, acc2 = 0.f, acc3 = 0.f;
#pragma unroll
    for (int ci = 0; ci < 32; ++ci) {
        acc0 += ib[0 * 32 + ci] * w[ci * 4 + 0];
        acc1 += ib[1 * 32 + ci] * w[ci * 4 + 1];
        acc2 += ib[2 * 32 + ci] * w[ci * 4 + 2];
        acc3 += ib[3 * 32 + ci] * w[ci * 4 + 3];
    }
    float acc = ((acc0 + acc1) + (acc2 + acc3)) + cb[level * 32 + co];
    acc = (acc - bm[level * 32 + co]) * rsqrtf(bv[level * 32 + co] + 1e-5f)
          * bg[level * 32 + co] + bb[level * 32 + co];
    acc = acc > 0.f ? acc : expm1f(acc);
    pooled[(size_t)(b * 672 + out_off + lo) * 32 + co] = acc;
}

// ---------------- build h rows (copy x | pooled@w_up+b_up) fused with LN0. wave per row.
__global__ void build_ln_kernel(const float* __restrict__ x, const float* __restrict__ pooled,
                                const float* __restrict__ w_up, const float* __restrict__ b_up,
                                const float* __restrict__ g, const float* __restrict__ bta,
                                float* __restrict__ h) {
    int wave = threadIdx.x >> 6;
    int lane = threadIdx.x & 63;
    int row = blockIdx.x * 4 + wave;          // 5440 rows
    int b = row / S_TOT, s = row % S_TOT;
    float v0, v1;
    if (s < 2048) {
        const float* xr = x + (size_t)(b * 2048 + s) * 128;
        v0 = xr[lane]; v1 = xr[lane + 64];
    } else {
        int p = s - 2048;
        const float* pr = pooled + (size_t)(b * 672 + p) * 32;
        float a0 = b_up[lane], a1 = b_up[lane + 64];
        float a2 = 0.f, a3 = 0.f;
#pragma unroll
        for (int k = 0; k < 32; k += 2) {
            float p0 = pr[k], p1 = pr[k + 1];
            a0 += p0 * w_up[k * 128 + lane];
            a1 += p0 * w_up[k * 128 + lane + 64];
            a2 += p1 * w_up[(k + 1) * 128 + lane];
            a3 += p1 * w_up[(k + 1) * 128 + lane + 64];
        }
        v0 = a0 + a2; v1 = a1 + a3;
    }
    float sum = v0 + v1;
#pragma unroll
    for (int off = 32; off; off >>= 1) sum += __shfl_xor(sum, off);
    float mu = sum * (1.f / 128.f);
    float d0 = v0 - mu, d1 = v1 - mu;
    float vs = d0 * d0 + d1 * d1;
#pragma unroll
    for (int off = 32; off; off >>= 1) vs += __shfl_xor(vs, off);
    float inv = rsqrtf(vs * (1.f / 128.f) + 1e-5f);
    h[(size_t)row * 128 + lane]      = d0 * inv * g[lane]      + bta[lane];
    h[(size_t)row * 128 + lane + 64] = d1 * inv * g[lane + 64] + bta[lane + 64];
}

// ---------------- fused QKV: per block 32 rows; wave w owns rows w*8..w*8+7, 64 lanes x 2 cols
__global__ __launch_bounds__(256) void qkv_kernel(const float* __restrict__ H,
                                                  const float* __restrict__ wq,
                                                  const float* __restrict__ wk,
                                                  const float* __restrict__ wv,
                                                  float* __restrict__ q, float* __restrict__ k,
                                                  float* __restrict__ v) {
    __shared__ float hs[32][128];
    int tid = threadIdx.x;
    int r0 = blockIdx.x * 32;
    {
        const float4* src = (const float4*)(H + (size_t)r0 * 128);
        float4* dst = (float4*)hs;
#pragma unroll
        for (int idx = 0; idx < 4; ++idx) dst[tid + idx * 256] = src[tid + idx * 256];
    }
    __syncthreads();
    int wv_ = tid >> 6, lane = tid & 63;
    int rbase = wv_ * 8, j0 = lane * 2;
    const float* W[3] = {wq, wk, wv};
    float* O[3] = {q, k, v};
    float acc[3][8][2];
#pragma unroll
    for (int m = 0; m < 3; ++m)
#pragma unroll
        for (int r = 0; r < 8; ++r) { acc[m][r][0] = 0.f; acc[m][r][1] = 0.f; }
    for (int kt = 0; kt < 128; kt += 4) {
        float4 haf[8];
#pragma unroll
        for (int r = 0; r < 8; ++r) haf[r] = *(const float4*)&hs[rbase + r][kt];
#pragma unroll
        for (int kk = 0; kk < 4; ++kk) {
            float2 wf[3];
#pragma unroll
            for (int m = 0; m < 3; ++m) wf[m] = *(const float2*)&W[m][(kt + kk) * 128 + j0];
#pragma unroll
            for (int r = 0; r < 8; ++r) {
                float hv = ((const float*)&haf[r])[kk];
#pragma unroll
                for (int m = 0; m < 3; ++m) {
                    acc[m][r][0] += hv * wf[m].x;
                    acc[m][r][1] += hv * wf[m].y;
                }
            }
        }
    }
#pragma unroll
    for (int m = 0; m < 3; ++m)
#pragma unroll
        for (int r = 0; r < 8; ++r)
            *(float2*)&O[m][(size_t)(r0 + rbase + r) * 128 + j0] =
                make_float2(acc[m][r][0], acc[m][r][1]);
}

// ---------------- sparse pyramid attention, 4 lanes per query (each owns 8 dims)
__global__ void attn_kernel(const float* __restrict__ Q, const float* __restrict__ K,
                            const float* __restrict__ V, float* __restrict__ O) {
    int id = blockIdx.x * 256 + threadIdx.x;     // 87040
    int d0 = (id & 3) * 8;
    int gid = id >> 2;                           // 21760 queries
    int i  = gid % S_TOT;
    int hh = (gid / S_TOT) & 3;
    int b  = gid / (S_TOT * 4);
    int li, s;
    if (i < 2048)      { li = 0; s = 0;    }
    else if (i < 2560) { li = 1; s = 2048; }
    else if (i < 2688) { li = 2; s = 2560; }
    else               { li = 3; s = 2688; }
    int sz = (li == 0) ? 2048 : (li == 1) ? 512 : (li == 2) ? 128 : 32;
    int pstart = (li == 0) ? 2048 : (li == 1) ? 2560 : 2688;
    int cstart = (li == 1) ? 0 : (li == 2) ? 2048 : 2560;

    const float* qp = Q + ((size_t)(b * S_TOT + i) * 128) + hh * 32 + d0;
    float4 qa = *(const float4*)qp;
    float4 qb = *(const float4*)(qp + 4);
    const float invt = 0.17677669529663687f;     // 1/sqrt(32)

    float sc[10];
    int   nj[10];
    bool  vl[10];
#pragma unroll
    for (int slot = 0; slot < 10; ++slot) {
        int j; bool valid;
        if (slot < 5)       { j = i - 2 + slot;                         valid = (j >= s) && (j < s + sz); }
        else if (slot == 5) { j = pstart + ((i - s) >> 2);              valid = (li < 3); }
        else                { j = cstart + ((i - s) << 2) + (slot - 6); valid = (li > 0); }
        nj[slot] = j; vl[slot] = valid;
        float dot = 0.f;
        if (valid) {
            const float* kp = K + ((size_t)(b * S_TOT + j) * 128) + hh * 32 + d0;
            float4 ka = *(const float4*)kp;
            float4 kb = *(const float4*)(kp + 4);
            dot = qa.x * ka.x + qa.y * ka.y + qa.z * ka.z + qa.w * ka.w
                + qb.x * kb.x + qb.y * kb.y + qb.z * kb.z + qb.w * kb.w;
        }
        dot += __shfl_xor(dot, 1);
        dot += __shfl_xor(dot, 2);
        sc[slot] = valid ? dot * invt : -1e30f;
    }
    float mx = sc[0];
#pragma unroll
    for (int slot = 1; slot < 10; ++slot) mx = fmaxf(mx, sc[slot]);
    float ssum = 0.f;
#pragma unroll
    for (int slot = 0; slot < 10; ++slot) { sc[slot] = __expf(sc[slot] - mx); ssum += sc[slot]; }
    float rinv = 1.f / ssum;
    float4 oa = {0.f, 0.f, 0.f, 0.f}, ob = {0.f, 0.f, 0.f, 0.f};
#pragma unroll
    for (int slot = 0; slot < 10; ++slot) {
        if (vl[slot]) {
            float p = sc[slot] * rinv;
            const float* vp = V + ((size_t)(b * S_TOT + nj[slot]) * 128) + hh * 32 + d0;
            float4 va = *(const float4*)vp;
            float4 vb = *(const float4*)(vp + 4);
            oa.x += p * va.x; oa.y += p * va.y; oa.z += p * va.z; oa.w += p * va.w;
            ob.x += p * vb.x; ob.y += p * vb.y; ob.z += p * vb.z; ob.w += p * vb.w;
        }
    }
    float* op = O + ((size_t)(b * S_TOT + i) * 128) + hh * 32 + d0;
    *(float4*)op = oa;
    *(float4*)(op + 4) = ob;
}

// ---------------- o-proj + residual + LN1, fused. 32 rows/block, wave owns 8 rows.
__global__ __launch_bounds__(256) void o_ln_kernel(const float* __restrict__ Ob,
                                                   const float* __restrict__ wo,
                                                   const float* __restrict__ g,
                                                   const float* __restrict__ bta,
                                                   float* __restrict__ h) {
    __shared__ float os[32][128];
    int tid = threadIdx.x;
    int r0 = blockIdx.x * 32;
    {
        const float4* src = (const float4*)(Ob + (size_t)r0 * 128);
        float4* dst = (float4*)os;
#pragma unroll
        for (int idx = 0; idx < 4; ++idx) dst[tid + idx * 256] = src[tid + idx * 256];
    }
    __syncthreads();
    int wv_ = tid >> 6, lane = tid & 63;
    int rbase = wv_ * 8, j0 = lane * 2;
    float acc[8][2];
#pragma unroll
    for (int r = 0; r < 8; ++r) { acc[r][0] = 0.f; acc[r][1] = 0.f; }
    for (int kt = 0; kt < 128; kt += 4) {
        float4 haf[8];
#pragma unroll
        for (int r = 0; r < 8; ++r) haf[r] = *(const float4*)&os[rbase + r][kt];
#pragma unroll
        for (int kk = 0; kk < 4; ++kk) {
            float2 wf = *(const float2*)&wo[(kt + kk) * 128 + j0];
#pragma unroll
            for (int r = 0; r < 8; ++r) {
                float hv = ((const float*)&haf[r])[kk];
                acc[r][0] += hv * wf.x;
                acc[r][1] += hv * wf.y;
            }
        }
    }
    float g0 = g[j0], g1 = g[j0 + 1], bt0 = bta[j0], bt1 = bta[j0 + 1];
#pragma unroll
    for (int r = 0; r < 8; ++r) {
        size_t row = (size_t)(r0 + rbase + r) * 128;
        float2 res = *(const float2*)&h[row + j0];
        float v0 = acc[r][0] + res.x, v1 = acc[r][1] + res.y;
        float sum = v0 + v1;
#pragma unroll
        for (int off = 32; off; off >>= 1) sum += __shfl_xor(sum, off);
        float mu = sum * (1.f / 128.f);
        float e0 = v0 - mu, e1 = v1 - mu;
        float vs = e0 * e0 + e1 * e1;
#pragma unroll
        for (int off = 32; off; off >>= 1) vs += __shfl_xor(vs, off);
        float inv = rsqrtf(vs * (1.f / 128.f) + 1e-6f);
        *(float2*)&h[row + j0] = make_float2(e0 * inv * g0 + bt0, e1 * inv * g1 + bt1);
    }
}

// ---------------- fused FFN + residual + LN2. 8 rows per block of 256.
__global__ __launch_bounds__(256) void ffn_kernel(const float* __restrict__ H,
                                                  const float* __restrict__ w1,
                                                  const float* __restrict__ b1,
                                                  const float* __restrict__ w2,
                                                  const float* __restrict__ b2,
                                                  const float* __restrict__ g,
                                                  const float* __restrict__ bta,
                                                  float* __restrict__ h) {
    __shared__ float hs[8][128];
    __shared__ float f1s[8][512];
    __shared__ float part[4][8][128];
    int tid = threadIdx.x;
    int r0 = blockIdx.x * 8;
    ((float4*)hs)[tid] = ((const float4*)(H + (size_t)r0 * 128))[tid];
    __syncthreads();
    // stage 1: thread owns cols j0, j0+1 of 512
    {
        int j0 = tid * 2;
        float acc[8][2];
#pragma unroll
        for (int r = 0; r < 8; ++r) { acc[r][0] = 0.f; acc[r][1] = 0.f; }
        for (int kt = 0; kt < 128; kt += 4) {
            float4 haf[8];
#pragma unroll
            for (int r = 0; r < 8; ++r) haf[r] = *(const float4*)&hs[r][kt];
#pragma unroll
            for (int kk = 0; kk < 4; ++kk) {
                float2 wf = *(const float2*)&w1[(kt + kk) * 512 + j0];
#pragma unroll
                for (int r = 0; r < 8; ++r) {
                    float hv = ((const float*)&haf[r])[kk];
                    acc[r][0] += hv * wf.x;
                    acc[r][1] += hv * wf.y;
                }
            }
        }
        float2 bv = *(const float2*)&b1[j0];
#pragma unroll
        for (int r = 0; r < 8; ++r)
            *(float2*)&f1s[r][j0] = make_float2(fmaxf(acc[r][0] + bv.x, 0.f),
                                                fmaxf(acc[r][1] + bv.y, 0.f));
    }
    __syncthreads();
    // stage 2: seg = tid>>6 covers 128 j's; thread owns d0, d0+1
    {
        int seg = tid >> 6, dp = tid & 63;
        int d0 = dp * 2, jb = seg * 128;
        float acc[8][2];
#pragma unroll
        for (int r = 0; r < 8; ++r) { acc[r][0] = 0.f; acc[r][1] = 0.f; }
        for (int jt = 0; jt < 128; jt += 4) {
            float4 faf[8];
#pragma unroll
            for (int r = 0; r < 8; ++r) faf[r] = *(const float4*)&f1s[r][jb + jt];
#pragma unroll
            for (int jj = 0; jj < 4; ++jj) {
                float2 wf = *(const float2*)&w2[(jb + jt + jj) * 128 + d0];
#pragma unroll
                for (int r = 0; r < 8; ++r) {
                    float fv = ((const float*)&faf[r])[jj];
                    acc[r][0] += fv * wf.x;
                    acc[r][1] += fv * wf.y;
                }
            }
        }
#pragma unroll
        for (int r = 0; r < 8; ++r)
            *(float2*)&part[seg][r][d0] = make_float2(acc[r][0], acc[r][1]);
    }
    __syncthreads();
    // final: combine segs + bias + residual + LN2. Row in 32 lanes x 4 vals.
    {
        int r = tid >> 5, dgrp = tid & 31, d0 = dgrp * 4;
        float4 s0 = *(const float4*)&part[0][r][d0];
        float4 s1 = *(const float4*)&part[1][r][d0];
        float4 s2 = *(const float4*)&part[2][r][d0];
        float4 s3 = *(const float4*)&part[3][r][d0];
        float4 bb = *(const float4*)&b2[d0];
        size_t row = (size_t)(r0 + r) * 128;
        float4 res = *(const float4*)&h[row + d0];
        float v0 = s0.x + s1.x + s2.x + s3.x + bb.x + res.x;
        float v1 = s0.y + s1.y + s2.y + s3.y + bb.y + res.y;
        float v2 = s0.z + s1.z + s2.z + s3.z + bb.z + res.z;
        float v3 = s0.w + s1.w + s2.w + s3.w + bb.w + res.w;
        float sum = (v0 + v1) + (v2 + v3);
#pragma unroll
        for (int off = 16; off; off >>= 1) sum += __shfl_xor(sum, off);
        float mu = sum * (1.f / 128.f);
        float e0 = v0 - mu, e1 = v1 - mu, e2 = v2 - mu, e3 = v3 - mu;
        float vs = (e0 * e0 + e1 * e1) + (e2 * e2 + e3 * e3);
#pragma unroll
        for (int off = 16; off; off >>= 1) vs += __shfl_xor(vs, off);
        float inv = rsqrtf(vs * (1.f / 128.f) + 1e-6f);
        float4 gv = *(const float4*)&g[d0];
        float4 bv = *(const float4*)&bta[d0];
        float4 outv = make_float4(e0 * inv * gv.x + bv.x, e1 * inv * gv.y + bv.y,
                                  e2 * inv * gv.z + bv.z, e3 * inv * gv.w + bv.w);
        *(float4*)&h[row + d0] = outv;
    }
}

// ---------------- gather refer-points, float4
__global__ void gather_kernel(const float* __restrict__ H, const int* __restrict__ idx,
                              float* __restrict__ out) {
    int id = blockIdx.x * 256 + threadIdx.x;     // 524288 float4s
    int d4 = id & 31;
    int j = (id >> 5) & 3;
    int t = (id >> 7) & 2047;
    int b = id >> 18;
    int src = idx[t * 4 + j];
    ((float4*)out)[id] = *(const float4*)&H[((size_t)(b * S_TOT + src) * 128) + d4 * 4];
}

extern "C" void kernel_launch(void* const* d_in, const int* in_sizes, int n_in,
                              void* d_out, int out_size, void* d_ws, size_t ws_size,
                              hipStream_t stream) {
    (void)in_sizes; (void)n_in; (void)out_size; (void)ws_size;
    const float* x       = (const float*)d_in[0];
    const float* w_down  = (const float*)d_in[1];
    const float* b_down  = (const float*)d_in[2];
    const float* conv_w  = (const float*)d_in[3];
    const float* conv_b  = (const float*)d_in[4];
    const float* bn_g    = (const float*)d_in[5];
    const float* bn_b    = (const float*)d_in[6];
    const float* bn_m    = (const float*)d_in[7];
    const float* bn_v    = (const float*)d_in[8];
    const float* w_up    = (const float*)d_in[9];
    const float* b_up    = (const float*)d_in[10];
    const float* ln0_g   = (const float*)d_in[11];
    const float* ln0_b   = (const float*)d_in[12];
    const float* wq      = (const float*)d_in[13];
    const float* wk      = (const float*)d_in[14];
    const float* wv      = (const float*)d_in[15];
    const float* wo      = (const float*)d_in[16];
    const float* ln1_g   = (const float*)d_in[17];
    const float* ln1_b   = (const float*)d_in[18];
    const float* ffn_w1  = (const float*)d_in[19];
    const float* ffn_b1  = (const float*)d_in[20];
    const float* ffn_w2  = (const float*)d_in[21];
    const float* ffn_b2  = (const float*)d_in[22];
    const float* ln2_g   = (const float*)d_in[23];
    const float* ln2_b   = (const float*)d_in[24];
    const int* indexes   = (const int*)d_in[26];

    float* ws = (float*)d_ws;
    float* t0     = ws;               // 131072
    float* pooled = ws + 131072;      // 43008
    float* h      = ws + 174080;      // 696320
    float* q      = ws + 870400;      // 696320
    float* k      = ws + 1566720;     // 696320
    float* v      = ws + 2263040;     // 696320
    float* o      = ws + 2959360;     // 696320

    down_kernel<<<512, 256, 0, stream>>>(x, w_down, b_down, t0);
    conv_kernel<<<128, 256, 0, stream>>>(t0, pooled, conv_w, conv_b, bn_g, bn_b, bn_m, bn_v,
                                         0, 2048, 0, 512, 0, 32768);
    conv_kernel<<<32, 256, 0, stream>>>(pooled, pooled, conv_w, conv_b, bn_g, bn_b, bn_m, bn_v,
                                        1, 672, 0, 128, 512, 8192);
    conv_kernel<<<8, 256, 0, stream>>>(pooled, pooled, conv_w, conv_b, bn_g, bn_b, bn_m, bn_v,
                                       2, 672, 512, 32, 640, 2048);
    build_ln_kernel<<<1360, 256, 0, stream>>>(x, pooled, w_up, b_up, ln0_g, ln0_b, h);

    for (int l = 0; l < 2; ++l) {
        qkv_kernel<<<170, 256, 0, stream>>>(h, wq + l * 16384, wk + l * 16384, wv + l * 16384,
                                            q, k, v);
        attn_kernel<<<340, 256, 0, stream>>>(q, k, v, o);
        o_ln_kernel<<<170, 256, 0, stream>>>(o, wo + l * 16384,
                                             ln1_g + l * 128, ln1_b + l * 128, h);
        ffn_kernel<<<680, 256, 0, stream>>>(h, ffn_w1 + l * 65536, ffn_b1 + l * 512,
                                            ffn_w2 + l * 65536, ffn_b2 + l * 128,
                                            ln2_g + l * 128, ln2_b + l * 128, h);
    }
    gather_kernel<<<2048, 256, 0, stream>>>(h, indexes, (float*)d_out);
}